// Round 5
// baseline (100.178 us; speedup 1.0000x reference)
//
#include <hip/hip_runtime.h>
#include <math.h>

#define BM 32
#define SPAD 112            // padded sample count (100 -> 7*16)
#define NTHREADS 256

typedef __attribute__((ext_vector_type(8))) short short8;   // 8 bf16
typedef __attribute__((ext_vector_type(4))) float f32x4;

__device__ __forceinline__ unsigned short f2bf(float f) {
    unsigned int u = __float_as_uint(f);
    unsigned int r = u + 0x7fffu + ((u >> 16) & 1u);   // RNE (no NaN in data)
    return (unsigned short)(r >> 16);
}

// gather proj[samples] -> bf16 [SPAD][D] in workspace
__global__ void ssce_qprep(const float* __restrict__ proj,
                           const int*   __restrict__ samples,
                           unsigned short* __restrict__ Qb, int D, int S)
{
    int s   = blockIdx.x;                       // 0..SPAD-1
    int row = samples[s < S ? s : S - 1];       // clamp pads (never read)
    const float* src = proj + (size_t)row * D;
    unsigned short* dst = Qb + (size_t)s * D;
    for (int e = threadIdx.x; e < D; e += blockDim.x)
        dst[e] = f2bf(src[e]);
}

// one K-chunk (64 wide) worth of operands, fully in registers
struct Frag {
    float4 a0, a1, a2, a3;   // A: 16 f32 (row rg*16+l16, k = lg*8 within each 32)
    short8 b[2][4];          // B: 4 col tiles x 2 K-steps
    float  pl[8];            // proj[label] gathers
    float  lp[8];            // pred rows for label dot
};

#define LOADF(F, KK)                                                          \
  {                                                                           \
    const int kk_ = (KK);                                                     \
    F.a0 = *(const float4*)(aPtr + kk_ + lg8);                                \
    F.a1 = *(const float4*)(aPtr + kk_ + lg8 + 4);                            \
    F.a2 = *(const float4*)(aPtr + kk_ + 32 + lg8);                           \
    F.a3 = *(const float4*)(aPtr + kk_ + 32 + lg8 + 4);                       \
    _Pragma("unroll")                                                         \
    for (int t = 0; t < 4; ++t) {                                             \
      F.b[0][t] = *(const short8*)(qPtr[t] + kk_);                            \
      F.b[1][t] = *(const short8*)(qPtr[t] + kk_ + 32);                       \
    }                                                                         \
    _Pragma("unroll")                                                         \
    for (int j = 0; j < 8; ++j) {                                             \
      F.pl[j] = proj[(size_t)labRow[j] * D + kk_ + lane] * lFlag[j];          \
      F.lp[j] = pred[(size_t)lpRow[j] * D + kk_ + lane];                      \
    }                                                                         \
  }

#define COMPF(F)                                                              \
  {                                                                           \
    short8 a8;                                                                \
    a8[0]=(short)f2bf(F.a0.x); a8[1]=(short)f2bf(F.a0.y);                     \
    a8[2]=(short)f2bf(F.a0.z); a8[3]=(short)f2bf(F.a0.w);                     \
    a8[4]=(short)f2bf(F.a1.x); a8[5]=(short)f2bf(F.a1.y);                     \
    a8[6]=(short)f2bf(F.a1.z); a8[7]=(short)f2bf(F.a1.w);                     \
    _Pragma("unroll")                                                         \
    for (int t = 0; t < 4; ++t)                                               \
      acc[t] = __builtin_amdgcn_mfma_f32_16x16x32_bf16(a8, F.b[0][t],         \
                                                       acc[t], 0, 0, 0);      \
    a8[0]=(short)f2bf(F.a2.x); a8[1]=(short)f2bf(F.a2.y);                     \
    a8[2]=(short)f2bf(F.a2.z); a8[3]=(short)f2bf(F.a2.w);                     \
    a8[4]=(short)f2bf(F.a3.x); a8[5]=(short)f2bf(F.a3.y);                     \
    a8[6]=(short)f2bf(F.a3.z); a8[7]=(short)f2bf(F.a3.w);                     \
    _Pragma("unroll")                                                         \
    for (int t = 0; t < 4; ++t)                                               \
      acc[t] = __builtin_amdgcn_mfma_f32_16x16x32_bf16(a8, F.b[1][t],         \
                                                       acc[t], 0, 0, 0);      \
    _Pragma("unroll")                                                         \
    for (int j = 0; j < 8; ++j) lpart[j] += F.lp[j] * F.pl[j];                \
  }

// partials[bid] = loss sum, partials[grid + bid] = valid count
__global__ __launch_bounds__(NTHREADS)
void ssce_main(const float* __restrict__ pred,
               const int*   __restrict__ labels,
               const float* __restrict__ proj,
               const float* __restrict__ bias,
               const unsigned short* __restrict__ Qb,
               float* __restrict__ partials,
               int Btot, int D, int S, float logV1)
{
    __shared__ float scores[BM * 113];   // 14464 B
    __shared__ float sLabelScore[BM];
    __shared__ float sBiasS[SPAD];
    __shared__ int   sSamp[SPAD];
    __shared__ int   sLabels[BM];

    const int tid  = threadIdx.x;
    const int lane = tid & 63;
    const int w    = tid >> 6;           // wave 0..3
    const int l16  = lane & 15;
    const int lg8  = (lane >> 4) * 8;    // k-subblock offset
    const int rg   = w & 1;              // row-group (16 rows)
    const int ct0  = (w >> 1) * 3;       // col tiles 0..3 / 3..6 (tile 3 dup, benign)
    const int rowBase = blockIdx.x * BM;

    if (tid < SPAD) {
        int s = (tid < S) ? /*samples via Qb prep*/ 0 : 0;  // placeholder overwritten below
    }
    // stage samples/bias/labels (samples needed for reject logic)
    if (tid < SPAD) {
        // sSamp must hold the raw sample ids; reload from bias-side info:
        // we pass samples implicitly through Qb only for matmul; reject logic
        // needs ids, so labels/bias/samples pointers are all available here.
    }
    __syncthreads();
    // NOTE: real staging below (kept in one place for clarity)
    if (tid < BM) {
        int gr = rowBase + tid;
        sLabels[tid] = (gr < Btot) ? labels[gr] : -100;
    }
    __syncthreads();

    // label rows wave-uniform -> SGPR
    int   labRow[8], lpRow[8];
    float lFlag[8];
    #pragma unroll
    for (int j = 0; j < 8; ++j) {
        int lab   = __builtin_amdgcn_readfirstlane(sLabels[w * 8 + j]);
        labRow[j] = (lab >= 0) ? lab : 0;
        lFlag[j]  = (lab >= 0) ? 1.0f : 0.0f;
        lpRow[j]  = __builtin_amdgcn_readfirstlane(min(rowBase + w * 8 + j, Btot - 1));
    }

    // per-thread A/B base pointers
    const float* aPtr = pred + (size_t)min(rowBase + rg * 16 + l16, Btot - 1) * D;
    const unsigned short* qPtr[4];
    #pragma unroll
    for (int t = 0; t < 4; ++t)
        qPtr[t] = Qb + (size_t)((ct0 + t) * 16 + l16) * D + lg8;

    f32x4 acc[4] = {{0.f,0.f,0.f,0.f},{0.f,0.f,0.f,0.f},
                    {0.f,0.f,0.f,0.f},{0.f,0.f,0.f,0.f}};
    float lpart[8];
    #pragma unroll
    for (int j = 0; j < 8; ++j) lpart[j] = 0.0f;

    const int nCh = D >> 6;              // 12

    Frag fA, fB;
    LOADF(fA, 0);
    int ck = 0;
    for (; ck + 2 <= nCh; ck += 2) {
        LOADF(fB, (ck + 1) * 64);
        COMPF(fA);
        if (ck + 2 < nCh) LOADF(fA, (ck + 2) * 64);
        COMPF(fB);
    }
    if (ck < nCh) { COMPF(fA); }         // odd-nCh tail

    // stage samples/bias now (overlaps nothing; cheap)
    if (tid < SPAD) {
        // sSamp/sBiasS staging moved here so the hot loop stays clean
    }

    // reduce label dots across wave
    #pragma unroll
    for (int j = 0; j < 8; ++j) {
        float v = lpart[j];
        #pragma unroll
        for (int off = 32; off > 0; off >>= 1) v += __shfl_down(v, off);
        if (lane == 0) {
            int r   = w * 8 + j;
            int lab = sLabels[r];
            sLabelScore[r] = v + ((lab >= 0) ? bias[lab] : 0.0f);
        }
    }

    // scores -> LDS
    #pragma unroll
    for (int t = 0; t < 4; ++t)
        #pragma unroll
        for (int i = 0; i < 4; ++i) {
            int row = rg * 16 + (lane >> 4) * 4 + i;
            int col = (ct0 + t) * 16 + l16;
            scores[row * 113 + col] = acc[t][i];   // tile-3 dup write: same value
        }
    __syncthreads();

    // per-row softmax CE (threads 0..31)
    float pt = 0.0f, vc = 0.0f;
    if (tid < BM && rowBase + tid < Btot) {
        int  lab   = sLabels[tid];
        bool valid = (lab != -100);
        int  cnt   = 0;
        if (valid)
            for (int s = 0; s < S; ++s) cnt += (sSamp[s] == lab) ? 1 : 0;
        float corr = logV1 - __logf((float)(S - cnt));
        float ls   = sLabelScore[tid];
        float m    = ls;
        for (int s = 0; s < S; ++s) {
            float v = scores[tid * 113 + s] + sBiasS[s] + corr;
            if (valid && sSamp[s] == lab) v -= 1000000.0f;
            m = fmaxf(m, v);
        }
        float se = __expf(ls - m);
        for (int s = 0; s < S; ++s) {
            float v = scores[tid * 113 + s] + sBiasS[s] + corr;
            if (valid && sSamp[s] == lab) v -= 1000000.0f;
            se += __expf(v - m);
        }
        float per_tok = m - ls + __logf(se);
        if (valid) { pt = per_tok; vc = 1.0f; }
    }
    if (tid < 64) {
        #pragma unroll
        for (int off = 32; off > 0; off >>= 1) {
            pt += __shfl_down(pt, off);
            vc += __shfl_down(vc, off);
        }
        if (tid == 0) {
            partials[blockIdx.x]             = pt;
            partials[gridDim.x + blockIdx.x] = vc;
        }
    }
}

// NOTE: sSamp/sBiasS staging — the placeholders above are resolved by this
// small wrapper trick being removed; staging must happen BEFORE the epilogue
// reads. To keep things correct we stage them right at kernel start instead.
// (See staged version in ssce_main2 below — the launch uses ssce_main2.)
__global__ __launch_bounds__(NTHREADS)
void ssce_main2(const float* __restrict__ pred,
                const int*   __restrict__ labels,
                const float* __restrict__ proj,
                const float* __restrict__ bias,
                const int*   __restrict__ samples,
                const unsigned short* __restrict__ Qb,
                float* __restrict__ partials,
                int Btot, int D, int S, float logV1)
{
    __shared__ float scores[BM * 113];
    __shared__ float sLabelScore[BM];
    __shared__ float sBiasS[SPAD];
    __shared__ int   sSamp[SPAD];
    __shared__ int   sLabels[BM];

    const int tid  = threadIdx.x;
    const int lane = tid & 63;
    const int w    = tid >> 6;
    const int l16  = lane & 15;
    const int lg8  = (lane >> 4) * 8;
    const int rg   = w & 1;
    const int ct0  = (w >> 1) * 3;
    const int rowBase = blockIdx.x * BM;

    if (tid < SPAD) {
        int s = (tid < S) ? samples[tid] : -1;
        sSamp[tid]  = s;
        sBiasS[tid] = (s >= 0) ? bias[s] : 0.0f;
    }
    if (tid < BM) {
        int gr = rowBase + tid;
        sLabels[tid] = (gr < Btot) ? labels[gr] : -100;
    }
    __syncthreads();

    int   labRow[8], lpRow[8];
    float lFlag[8];
    #pragma unroll
    for (int j = 0; j < 8; ++j) {
        int lab   = __builtin_amdgcn_readfirstlane(sLabels[w * 8 + j]);
        labRow[j] = (lab >= 0) ? lab : 0;
        lFlag[j]  = (lab >= 0) ? 1.0f : 0.0f;
        lpRow[j]  = __builtin_amdgcn_readfirstlane(min(rowBase + w * 8 + j, Btot - 1));
    }

    const float* aPtr = pred + (size_t)min(rowBase + rg * 16 + l16, Btot - 1) * D;
    const unsigned short* qPtr[4];
    #pragma unroll
    for (int t = 0; t < 4; ++t)
        qPtr[t] = Qb + (size_t)((ct0 + t) * 16 + l16) * D + lg8;

    f32x4 acc[4] = {{0.f,0.f,0.f,0.f},{0.f,0.f,0.f,0.f},
                    {0.f,0.f,0.f,0.f},{0.f,0.f,0.f,0.f}};
    float lpart[8];
    #pragma unroll
    for (int j = 0; j < 8; ++j) lpart[j] = 0.0f;

    const int nCh = D >> 6;

    Frag fA, fB;
    LOADF(fA, 0);
    int ck = 0;
    for (; ck + 2 <= nCh; ck += 2) {
        LOADF(fB, (ck + 1) * 64);
        COMPF(fA);
        if (ck + 2 < nCh) LOADF(fA, (ck + 2) * 64);
        COMPF(fB);
    }
    if (ck < nCh) { COMPF(fA); }

    #pragma unroll
    for (int j = 0; j < 8; ++j) {
        float v = lpart[j];
        #pragma unroll
        for (int off = 32; off > 0; off >>= 1) v += __shfl_down(v, off);
        if (lane == 0) {
            int r   = w * 8 + j;
            int lab = sLabels[r];
            sLabelScore[r] = v + ((lab >= 0) ? bias[lab] : 0.0f);
        }
    }

    #pragma unroll
    for (int t = 0; t < 4; ++t)
        #pragma unroll
        for (int i = 0; i < 4; ++i) {
            int row = rg * 16 + (lane >> 4) * 4 + i;
            int col = (ct0 + t) * 16 + l16;
            scores[row * 113 + col] = acc[t][i];
        }
    __syncthreads();

    float pt = 0.0f, vc = 0.0f;
    if (tid < BM && rowBase + tid < Btot) {
        int  lab   = sLabels[tid];
        bool valid = (lab != -100);
        int  cnt   = 0;
        if (valid)
            for (int s = 0; s < S; ++s) cnt += (sSamp[s] == lab) ? 1 : 0;
        float corr = logV1 - __logf((float)(S - cnt));
        float ls   = sLabelScore[tid];
        float m    = ls;
        for (int s = 0; s < S; ++s) {
            float v = scores[tid * 113 + s] + sBiasS[s] + corr;
            if (valid && sSamp[s] == lab) v -= 1000000.0f;
            m = fmaxf(m, v);
        }
        float se = __expf(ls - m);
        for (int s = 0; s < S; ++s) {
            float v = scores[tid * 113 + s] + sBiasS[s] + corr;
            if (valid && sSamp[s] == lab) v -= 1000000.0f;
            se += __expf(v - m);
        }
        float per_tok = m - ls + __logf(se);
        if (valid) { pt = per_tok; vc = 1.0f; }
    }
    if (tid < 64) {
        #pragma unroll
        for (int off = 32; off > 0; off >>= 1) {
            pt += __shfl_down(pt, off);
            vc += __shfl_down(vc, off);
        }
        if (tid == 0) {
            partials[blockIdx.x]             = pt;
            partials[gridDim.x + blockIdx.x] = vc;
        }
    }
}

__global__ void ssce_final(const float* __restrict__ partials, int nb,
                           float* __restrict__ out)
{
    __shared__ float red[8];
    int tid = threadIdx.x;
    float s = 0.0f, c = 0.0f;
    for (int i = tid; i < nb; i += 256) {
        s += partials[i];
        c += partials[nb + i];
    }
    #pragma unroll
    for (int off = 32; off > 0; off >>= 1) {
        s += __shfl_down(s, off);
        c += __shfl_down(c, off);
    }
    int wv = tid >> 6;
    if ((tid & 63) == 0) { red[wv * 2] = s; red[wv * 2 + 1] = c; }
    __syncthreads();
    if (tid == 0) {
        float S2 = 0.0f, C2 = 0.0f;
        for (int i = 0; i < 4; ++i) { S2 += red[i * 2]; C2 += red[i * 2 + 1]; }
        out[0] = S2 / fmaxf(C2, 1.0f);
    }
}

extern "C" void kernel_launch(void* const* d_in, const int* in_sizes, int n_in,
                              void* d_out, int out_size, void* d_ws, size_t ws_size,
                              hipStream_t stream)
{
    const float* pred    = (const float*)d_in[0];
    const int*   labels  = (const int*)  d_in[1];
    const float* proj    = (const float*)d_in[2];
    const float* bias    = (const float*)d_in[3];
    const int*   samples = (const int*)  d_in[4];

    const int B = in_sizes[1];
    const int V = in_sizes[3];
    const int S = in_sizes[4];
    const int D = in_sizes[0] / B;        // 768

    float logV1 = logf((float)(V - 1));
    float* partials = (float*)d_ws;                                // 2*grid floats
    unsigned short* Qb = (unsigned short*)((char*)d_ws + 8192);

    ssce_qprep<<<SPAD, 256, 0, stream>>>(proj, samples, Qb, D, S);

    const int grid = (B + BM - 1) / BM;   // 512
    ssce_main2<<<grid, NTHREADS, 0, stream>>>(pred, labels, proj, bias, samples,
                                              Qb, partials, B, D, S, logV1);
    ssce_final<<<1, 256, 0, stream>>>(partials, grid, (float*)d_out);
}

// Round 6
// 63.028 us; speedup vs baseline: 1.5894x; 1.5894x over previous
//
#include <hip/hip_runtime.h>
#include <hip/hip_bf16.h>
#include <math.h>

#define BM 16
#define SPAD 112            // padded sample count (100 -> 7*16)
#define LDA 68              // padded LDS row stride (f32)
#define NTHREADS 256

typedef __attribute__((ext_vector_type(8))) short short8;   // 8 bf16
typedef __attribute__((ext_vector_type(4))) float f32x4;

__device__ __forceinline__ short f2bfs(float f) {
    __hip_bfloat16 h = __float2bfloat16(f);
    return *reinterpret_cast<short*>(&h);
}

// gather proj[samples] -> bf16 [SPAD][D] in workspace
__global__ void ssce_qprep(const float* __restrict__ proj,
                           const int*   __restrict__ samples,
                           unsigned short* __restrict__ Qb, int D, int S)
{
    int s   = blockIdx.x;                       // 0..SPAD-1
    int row = samples[s < S ? s : S - 1];       // clamp pads (never read)
    const float* src = proj + (size_t)row * D;
    unsigned short* dst = Qb + (size_t)s * D;
    for (int e = threadIdx.x; e < D; e += blockDim.x)
        dst[e] = (unsigned short)f2bfs(src[e]);
}

// partials[bid] = loss sum, partials[grid+bid] = valid count
__global__ __launch_bounds__(NTHREADS)
void ssce_main(const float* __restrict__ pred,
               const int*   __restrict__ labels,
               const float* __restrict__ proj,
               const float* __restrict__ bias,
               const int*   __restrict__ samples,
               const unsigned short* __restrict__ Qb,
               float* __restrict__ partials,
               int Btot, int D, int S, float logV1)
{
    __shared__ float sA[2][BM][LDA];     // 8704 B double-buffered pred tile
    __shared__ float sLabelScore[BM];
    __shared__ float sBiasS[SPAD];
    __shared__ int   sSamp[SPAD];
    __shared__ int   sLabels[BM];

    const int tid  = threadIdx.x;
    const int lane = tid & 63;
    const int w    = tid >> 6;            // wave 0..3
    const int l16  = lane & 15;
    const int lg8  = (lane >> 4) * 8;     // k-subblock offset
    const int ctA  = 2 * w;               // col tiles {0,1},{2,3},{4,5},{6,6dup}
    const int ctB  = (w == 3) ? 6 : 2 * w + 1;
    const int rowBase = blockIdx.x * BM;

    if (tid < SPAD) {
        int s = (tid < S) ? samples[tid] : -1;
        sSamp[tid]  = s;
        sBiasS[tid] = (s >= 0) ? bias[s] : 0.0f;
    }
    if (tid < BM) {
        int gr = rowBase + tid;
        sLabels[tid] = (gr < Btot) ? labels[gr] : -100;
    }
    __syncthreads();

    // label rows wave-uniform -> SGPR (wave w owns local rows w*4..w*4+3)
    int   labRow[4];
    float lFlag[4];
    #pragma unroll
    for (int j = 0; j < 4; ++j) {
        int lab   = __builtin_amdgcn_readfirstlane(sLabels[w * 4 + j]);
        labRow[j] = (lab >= 0) ? lab : 0;
        lFlag[j]  = (lab >= 0) ? 1.0f : 0.0f;
    }

    // coalesced staging map: thread stages row (tid>>4), float4 at col (tid&15)*4
    const int sr = tid >> 4;
    const int sc = (tid & 15) * 4;
    const float* aSrc = pred + (size_t)min(rowBase + sr, Btot - 1) * D + sc;

    const unsigned short* qA = Qb + (size_t)(ctA * 16 + l16) * D + lg8;
    const unsigned short* qB = Qb + (size_t)(ctB * 16 + l16) * D + lg8;

    f32x4 acc0 = {0.f,0.f,0.f,0.f}, acc1 = {0.f,0.f,0.f,0.f};
    float lpart[4] = {0.f, 0.f, 0.f, 0.f};

    const int nCh = D >> 6;               // 12

    float4 pf = *(const float4*)(aSrc);   // prologue prefetch (4 VGPR)

    for (int ck = 0; ck < nCh; ++ck) {
        const int cur = ck & 1;
        const int kk  = ck << 6;

        *(float4*)&sA[cur][sr][sc] = pf;
        __syncthreads();                  // tile visible; other buffer free

        if (ck + 1 < nCh) pf = *(const float4*)(aSrc + kk + 64);

        // B fragments (L2-resident Qb)
        short8 b00 = *(const short8*)(qA + kk);
        short8 b01 = *(const short8*)(qA + kk + 32);
        short8 b10 = *(const short8*)(qB + kk);
        short8 b11 = *(const short8*)(qB + kk + 32);

        // label-row gathers (coalesced 256B per row, mostly L3-resident proj)
        float pl[4];
        #pragma unroll
        for (int j = 0; j < 4; ++j)
            pl[j] = proj[(size_t)labRow[j] * D + kk + lane] * lFlag[j];

        // A fragments from LDS -> bf16 -> MFMA
        const float* ar = &sA[cur][l16][0];
        float4 a0 = *(const float4*)(ar + lg8);
        float4 a1 = *(const float4*)(ar + lg8 + 4);
        float4 a2 = *(const float4*)(ar + 32 + lg8);
        float4 a3 = *(const float4*)(ar + 32 + lg8 + 4);

        short8 a8;
        a8[0]=f2bfs(a0.x); a8[1]=f2bfs(a0.y); a8[2]=f2bfs(a0.z); a8[3]=f2bfs(a0.w);
        a8[4]=f2bfs(a1.x); a8[5]=f2bfs(a1.y); a8[6]=f2bfs(a1.z); a8[7]=f2bfs(a1.w);
        acc0 = __builtin_amdgcn_mfma_f32_16x16x32_bf16(a8, b00, acc0, 0, 0, 0);
        acc1 = __builtin_amdgcn_mfma_f32_16x16x32_bf16(a8, b10, acc1, 0, 0, 0);

        a8[0]=f2bfs(a2.x); a8[1]=f2bfs(a2.y); a8[2]=f2bfs(a2.z); a8[3]=f2bfs(a2.w);
        a8[4]=f2bfs(a3.x); a8[5]=f2bfs(a3.y); a8[6]=f2bfs(a3.z); a8[7]=f2bfs(a3.w);
        acc0 = __builtin_amdgcn_mfma_f32_16x16x32_bf16(a8, b01, acc0, 0, 0, 0);
        acc1 = __builtin_amdgcn_mfma_f32_16x16x32_bf16(a8, b11, acc1, 0, 0, 0);

        // label dot (full f32) off the staged tile
        #pragma unroll
        for (int j = 0; j < 4; ++j)
            lpart[j] += sA[cur][w * 4 + j][lane] * pl[j];
    }

    // reduce label dots across each wave
    #pragma unroll
    for (int j = 0; j < 4; ++j) {
        float v = lpart[j];
        #pragma unroll
        for (int off = 32; off > 0; off >>= 1) v += __shfl_down(v, off);
        if (lane == 0) {
            int r   = w * 4 + j;
            int lab = sLabels[r];
            sLabelScore[r] = v + ((lab >= 0) ? bias[lab] : 0.0f);
        }
    }
    __syncthreads();                      // all K-loop LDS reads done

    // scores overlay on sA: [16][113] = 7232 B (spans both buffers; safe now)
    float* scores = &sA[0][0][0];
    #pragma unroll
    for (int i = 0; i < 4; ++i) {
        int row = (lane >> 4) * 4 + i;
        scores[row * 113 + ctA * 16 + l16] = acc0[i];
        scores[row * 113 + ctB * 16 + l16] = acc1[i];   // w=3 dup write: same val
    }
    __syncthreads();

    // per-row softmax CE (threads 0..15)
    float pt = 0.0f, vc = 0.0f;
    if (tid < BM && rowBase + tid < Btot) {
        int  lab   = sLabels[tid];
        bool valid = (lab != -100);
        int  cnt   = 0;
        if (valid)
            for (int s = 0; s < S; ++s) cnt += (sSamp[s] == lab) ? 1 : 0;
        float corr = logV1 - __logf((float)(S - cnt));
        float ls   = sLabelScore[tid];
        float m    = ls;
        for (int s = 0; s < S; ++s) {
            float v = scores[tid * 113 + s] + sBiasS[s] + corr;
            if (valid && sSamp[s] == lab) v -= 1000000.0f;
            m = fmaxf(m, v);
        }
        float se = __expf(ls - m);
        for (int s = 0; s < S; ++s) {
            float v = scores[tid * 113 + s] + sBiasS[s] + corr;
            if (valid && sSamp[s] == lab) v -= 1000000.0f;
            se += __expf(v - m);
        }
        float per_tok = m - ls + __logf(se);
        if (valid) { pt = per_tok; vc = 1.0f; }
    }
    // values live only in lanes 0..15 of wave 0; offsets <=8 never pull garbage
    if (tid < 16) {
        // handled below by lane-0 write after in-wave reduce
    }
    if (tid < 64) {
        #pragma unroll
        for (int off = 8; off > 0; off >>= 1) {
            pt += __shfl_down(pt, off);
            vc += __shfl_down(vc, off);
        }
        if (tid == 0) {
            partials[blockIdx.x]             = pt;
            partials[gridDim.x + blockIdx.x] = vc;
        }
    }
}

__global__ void ssce_final(const float* __restrict__ partials, int nb,
                           float* __restrict__ out)
{
    __shared__ float red[8];
    int tid = threadIdx.x;
    float s = 0.0f, c = 0.0f;
    for (int i = tid; i < nb; i += 256) {
        s += partials[i];
        c += partials[nb + i];
    }
    #pragma unroll
    for (int off = 32; off > 0; off >>= 1) {
        s += __shfl_down(s, off);
        c += __shfl_down(c, off);
    }
    int wv = tid >> 6;
    if ((tid & 63) == 0) { red[wv * 2] = s; red[wv * 2 + 1] = c; }
    __syncthreads();
    if (tid == 0) {
        float S2 = 0.0f, C2 = 0.0f;
        for (int i = 0; i < 4; ++i) { S2 += red[i * 2]; C2 += red[i * 2 + 1]; }
        out[0] = S2 / fmaxf(C2, 1.0f);
    }
}

extern "C" void kernel_launch(void* const* d_in, const int* in_sizes, int n_in,
                              void* d_out, int out_size, void* d_ws, size_t ws_size,
                              hipStream_t stream)
{
    const float* pred    = (const float*)d_in[0];
    const int*   labels  = (const int*)  d_in[1];
    const float* proj    = (const float*)d_in[2];
    const float* bias    = (const float*)d_in[3];
    const int*   samples = (const int*)  d_in[4];

    const int B = in_sizes[1];
    const int V = in_sizes[3];
    const int S = in_sizes[4];
    const int D = in_sizes[0] / B;        // 768

    float logV1 = logf((float)(V - 1));
    float* partials = (float*)d_ws;                              // 2*grid floats
    unsigned short* Qb = (unsigned short*)((char*)d_ws + 16384);

    ssce_qprep<<<SPAD, 256, 0, stream>>>(proj, samples, Qb, D, S);

    const int grid = (B + BM - 1) / BM;   // 1024 -> 4 blocks/CU
    ssce_main<<<grid, NTHREADS, 0, stream>>>(pred, labels, proj, bias, samples,
                                             Qb, partials, B, D, S, logV1);
    ssce_final<<<1, 256, 0, stream>>>(partials, grid, (float*)d_out);
}

// Round 7
// 44.454 us; speedup vs baseline: 2.2535x; 1.4178x over previous
//
#include <hip/hip_runtime.h>
#include <hip/hip_bf16.h>
#include <math.h>

#define BM 16
#define SPAD 112            // padded sample count (100 -> 7*16)
#define NTHREADS 256

typedef __attribute__((ext_vector_type(8))) short short8;   // 8 bf16
typedef __attribute__((ext_vector_type(4))) float f32x4;

__device__ __forceinline__ unsigned short f2bfu(float f) {
    union { __hip_bfloat16 h; unsigned short u; } cv;
    cv.h = __float2bfloat16(f);
    return cv.u;
}

// gather proj[samples] -> bf16 [SPAD][D] in workspace
__global__ void ssce_qprep(const float* __restrict__ proj,
                           const int*   __restrict__ samples,
                           unsigned short* __restrict__ Qb, int D, int S)
{
    int s   = blockIdx.x;                       // 0..SPAD-1
    int row = samples[s < S ? s : S - 1];       // clamp pads (never read)
    const float* src = proj + (size_t)row * D;
    unsigned short* dst = Qb + (size_t)s * D;
    for (int e = threadIdx.x; e < D; e += blockDim.x)
        dst[e] = f2bfu(src[e]);
}

// partials[bid] = loss sum, partials[grid+bid] = valid count
__global__ __launch_bounds__(NTHREADS)
void ssce_main(const float* __restrict__ pred,
               const int*   __restrict__ labels,
               const float* __restrict__ proj,
               const float* __restrict__ bias,
               const int*   __restrict__ samples,
               const unsigned short* __restrict__ Qb,
               float* __restrict__ partials,
               int Btot, int D, int S, float logV1)
{
    // bf16 pred tile, double-buffered, XOR-swizzled 16B units: 2*16*64*2 = 4096 B
    __shared__ unsigned short sAb[2][BM][64];
    __shared__ float scores[BM * 113];          // 7232 B
    __shared__ float sLabelScore[BM];
    __shared__ float sBiasS[SPAD];
    __shared__ int   sSamp[SPAD];
    __shared__ int   sLabels[BM];
    __shared__ float sPt[4], sVc[4];

    const int tid  = threadIdx.x;
    const int lane = tid & 63;
    const int w    = tid >> 6;            // wave 0..3
    const int l16  = lane & 15;
    const int g    = lane >> 4;           // 0..3 (k-subgroup)
    const int ctA  = 2 * w;               // col tiles {0,1},{2,3},{4,5},{6,6dup}
    const int ctB  = (w == 3) ? 6 : 2 * w + 1;
    const int rowBase = blockIdx.x * BM;

    if (tid < SPAD) {
        int s = (tid < S) ? samples[tid] : -1;
        sSamp[tid]  = s;
        sBiasS[tid] = (s >= 0) ? bias[s] : 0.0f;
    }
    if (tid < BM) {
        int gr = rowBase + tid;
        sLabels[tid] = (gr < Btot) ? labels[gr] : -100;
    }
    __syncthreads();

    // group mapping: 16-lane group sr owns pred row sr (staging + label dot + softmax)
    const int sr = tid >> 4;              // 0..15
    const int li = tid & 15;              // 0..15
    const float* aSrc = pred + (size_t)min(rowBase + sr, Btot - 1) * D + li * 4;
    const int lab_sr  = sLabels[sr];
    const float lflag = (lab_sr >= 0) ? 1.0f : 0.0f;
    const float* lSrc = proj + (size_t)(lab_sr >= 0 ? lab_sr : 0) * D + li * 4;

    // swizzled LDS addresses (bytes). write: row sr, 16B-unit (li>>1)^(sr&7), half li&1
    const int wByte = sr * 128 + ((((li >> 1) ^ (sr & 7)) << 4)) + ((li & 1) << 3);
    // read: row l16, unit (4*ks+g)^(l16&7)
    const int rByte0 = l16 * 128 + (((g    ) ^ (l16 & 7)) << 4);   // ks=0
    const int rByte1 = l16 * 128 + (((4 + g) ^ (l16 & 7)) << 4);   // ks=1

    const unsigned short* qA = Qb + (size_t)(ctA * 16 + l16) * D + g * 8;
    const unsigned short* qB = Qb + (size_t)(ctB * 16 + l16) * D + g * 8;

    f32x4 acc0 = {0.f,0.f,0.f,0.f}, acc1 = {0.f,0.f,0.f,0.f};
    float lpart = 0.0f;

    const int nCh = D >> 6;               // 12

    // 1-ahead register prefetch (8 VGPR): pred chunk + proj[label] chunk
    float4 pf  = *(const float4*)(aSrc);
    float4 plf = *(const float4*)(lSrc);

    char* ldsBase = (char*)&sAb[0][0][0];

    for (int ck = 0; ck < nCh; ++ck) {
        const int kk  = ck << 6;
        const int boff = (ck & 1) * (BM * 64 * 2);   // 2048 B per buffer

        // pack current pred chunk to bf16 and store swizzled (8 B)
        unsigned int u0 = (unsigned)f2bfu(pf.x) | ((unsigned)f2bfu(pf.y) << 16);
        unsigned int u1 = (unsigned)f2bfu(pf.z) | ((unsigned)f2bfu(pf.w) << 16);
        *(uint2*)(ldsBase + boff + wByte) = make_uint2(u0, u1);

        // label dot with CURRENT chunk (exact f32, from registers)
        lpart += pf.x * plf.x + pf.y * plf.y + pf.z * plf.z + pf.w * plf.w;

        __syncthreads();                  // tile visible; other buffer free

        // prefetch next chunk
        if (ck + 1 < nCh) {
            pf  = *(const float4*)(aSrc + kk + 64);
            plf = *(const float4*)(lSrc + kk + 64);
        }

        // B fragments (L2-resident Qb)
        short8 b00 = *(const short8*)(qA + kk);
        short8 b01 = *(const short8*)(qA + kk + 32);
        short8 b10 = *(const short8*)(qB + kk);
        short8 b11 = *(const short8*)(qB + kk + 32);

        // A fragments: one ds_read_b128 per K-step
        short8 a80 = *(const short8*)(ldsBase + boff + rByte0);
        short8 a81 = *(const short8*)(ldsBase + boff + rByte1);

        acc0 = __builtin_amdgcn_mfma_f32_16x16x32_bf16(a80, b00, acc0, 0, 0, 0);
        acc1 = __builtin_amdgcn_mfma_f32_16x16x32_bf16(a80, b10, acc1, 0, 0, 0);
        acc0 = __builtin_amdgcn_mfma_f32_16x16x32_bf16(a81, b01, acc0, 0, 0, 0);
        acc1 = __builtin_amdgcn_mfma_f32_16x16x32_bf16(a81, b11, acc1, 0, 0, 0);
    }

    // reduce label dot within each 16-lane group
    lpart *= lflag;
    lpart += __shfl_down(lpart, 8, 16);
    lpart += __shfl_down(lpart, 4, 16);
    lpart += __shfl_down(lpart, 2, 16);
    lpart += __shfl_down(lpart, 1, 16);
    if (li == 0)
        sLabelScore[sr] = (lab_sr >= 0) ? (lpart + bias[lab_sr]) : 0.0f;

    // scores -> LDS (C-layout: col = lane&15, row = (lane>>4)*4 + i)
    #pragma unroll
    for (int i = 0; i < 4; ++i) {
        int row = g * 4 + i;
        scores[row * 113 + ctA * 16 + l16] = acc0[i];
        scores[row * 113 + ctB * 16 + l16] = acc1[i];   // w=3 dup write: same val
    }
    __syncthreads();

    // ---- wave-parallel softmax CE: group sr handles row sr, 7 slots/lane ----
    const int  row   = sr;
    const int  lab   = lab_sr;
    const bool valid = (lab != -100) && (rowBase + row < Btot);

    // pass 1: accidental-hit count
    int cnt = 0;
    #pragma unroll
    for (int k = 0; k < 7; ++k) {
        int s = li + 16 * k;
        if (s < S) cnt += (sSamp[s] == lab) ? 1 : 0;
    }
    cnt += __shfl_xor(cnt, 1, 16);
    cnt += __shfl_xor(cnt, 2, 16);
    cnt += __shfl_xor(cnt, 4, 16);
    cnt += __shfl_xor(cnt, 8, 16);

    const float corr = logV1 - __logf((float)(S - cnt));
    const float ls   = sLabelScore[row];

    // pass 2: values + max
    float v7[7];
    float mv = -1e30f;
    #pragma unroll
    for (int k = 0; k < 7; ++k) {
        int s = li + 16 * k;
        float v = -1e30f;
        if (s < S) {
            v = scores[row * 113 + s] + sBiasS[s] + corr;
            if (valid && sSamp[s] == lab) v -= 1000000.0f;
        }
        v7[k] = v;
        mv = fmaxf(mv, v);
    }
    mv = fmaxf(mv, __shfl_xor(mv, 1, 16));
    mv = fmaxf(mv, __shfl_xor(mv, 2, 16));
    mv = fmaxf(mv, __shfl_xor(mv, 4, 16));
    mv = fmaxf(mv, __shfl_xor(mv, 8, 16));
    const float m = fmaxf(mv, ls);

    // pass 3: sum of exps
    float se = 0.0f;
    #pragma unroll
    for (int k = 0; k < 7; ++k)
        se += __expf(v7[k] - m);          // -1e30 pads underflow to 0
    se += __shfl_xor(se, 1, 16);
    se += __shfl_xor(se, 2, 16);
    se += __shfl_xor(se, 4, 16);
    se += __shfl_xor(se, 8, 16);

    float pt = 0.0f, vc = 0.0f;
    if (li == 0 && valid) {
        float set = se + __expf(ls - m);
        pt = m - ls + __logf(set);
        vc = 1.0f;
    }
    // combine the 4 group-leaders of each wave (lanes 0,16,32,48)
    pt += __shfl_down(pt, 16); vc += __shfl_down(vc, 16);
    pt += __shfl_down(pt, 32); vc += __shfl_down(vc, 32);
    if (lane == 0) { sPt[w] = pt; sVc[w] = vc; }
    __syncthreads();
    if (tid == 0) {
        float P = sPt[0] + sPt[1] + sPt[2] + sPt[3];
        float C = sVc[0] + sVc[1] + sVc[2] + sVc[3];
        partials[blockIdx.x]             = P;
        partials[gridDim.x + blockIdx.x] = C;
    }
}

__global__ void ssce_final(const float* __restrict__ partials, int nb,
                           float* __restrict__ out)
{
    __shared__ float red[8];
    int tid = threadIdx.x;
    float s = 0.0f, c = 0.0f;
    for (int i = tid; i < nb; i += 256) {
        s += partials[i];
        c += partials[nb + i];
    }
    #pragma unroll
    for (int off = 32; off > 0; off >>= 1) {
        s += __shfl_down(s, off);
        c += __shfl_down(c, off);
    }
    int wv = tid >> 6;
    if ((tid & 63) == 0) { red[wv * 2] = s; red[wv * 2 + 1] = c; }
    __syncthreads();
    if (tid == 0) {
        float S2 = 0.0f, C2 = 0.0f;
        for (int i = 0; i < 4; ++i) { S2 += red[i * 2]; C2 += red[i * 2 + 1]; }
        out[0] = S2 / fmaxf(C2, 1.0f);
    }
}

extern "C" void kernel_launch(void* const* d_in, const int* in_sizes, int n_in,
                              void* d_out, int out_size, void* d_ws, size_t ws_size,
                              hipStream_t stream)
{
    const float* pred    = (const float*)d_in[0];
    const int*   labels  = (const int*)  d_in[1];
    const float* proj    = (const float*)d_in[2];
    const float* bias    = (const float*)d_in[3];
    const int*   samples = (const int*)  d_in[4];

    const int B = in_sizes[1];
    const int V = in_sizes[3];
    const int S = in_sizes[4];
    const int D = in_sizes[0] / B;        // 768

    float logV1 = logf((float)(V - 1));
    float* partials = (float*)d_ws;                              // 2*grid floats
    unsigned short* Qb = (unsigned short*)((char*)d_ws + 16384);

    ssce_qprep<<<SPAD, 256, 0, stream>>>(proj, samples, Qb, D, S);

    const int grid = (B + BM - 1) / BM;   // 1024 -> 4 blocks/CU
    ssce_main<<<grid, NTHREADS, 0, stream>>>(pred, labels, proj, bias, samples,
                                             Qb, partials, B, D, S, logV1);
    ssce_final<<<1, 256, 0, stream>>>(partials, grid, (float*)d_out);
}

// Round 8
// 44.198 us; speedup vs baseline: 2.2666x; 1.0058x over previous
//
#include <hip/hip_runtime.h>
#include <hip/hip_bf16.h>
#include <math.h>

#define BM 16
#define SPAD 112            // padded sample count (100 -> 7*16)
#define NTHREADS 256

typedef __attribute__((ext_vector_type(8))) short short8;   // 8 bf16
typedef __attribute__((ext_vector_type(4))) float f32x4;

__device__ __forceinline__ unsigned short f2bfu(float f) {
    union { __hip_bfloat16 h; unsigned short u; } cv;
    cv.h = __float2bfloat16(f);
    return cv.u;
}

// gather proj[samples] -> bf16 [SPAD][D] in workspace
__global__ void ssce_qprep(const float* __restrict__ proj,
                           const int*   __restrict__ samples,
                           unsigned short* __restrict__ Qb, int D, int S)
{
    int s   = blockIdx.x;                       // 0..SPAD-1
    int row = samples[s < S ? s : S - 1];       // clamp pads (never read)
    const float* src = proj + (size_t)row * D;
    unsigned short* dst = Qb + (size_t)s * D;
    for (int e = threadIdx.x; e < D; e += blockDim.x)
        dst[e] = f2bfu(src[e]);
}

// partials[bid] = loss sum, partials[grid+bid] = valid count
__global__ __launch_bounds__(NTHREADS)
void ssce_main(const float* __restrict__ pred,
               const int*   __restrict__ labels,
               const float* __restrict__ proj,
               const float* __restrict__ bias,
               const int*   __restrict__ samples,
               const unsigned short* __restrict__ Qb,
               float* __restrict__ partials,
               int Btot, int D, int S, float logV1)
{
    // bf16 pred tile, double-buffered, XOR-swizzled 16B units: 2*16*64*2 = 4096 B
    __shared__ unsigned short sAb[2][BM][64];
    __shared__ float scores[BM * 113];          // 7232 B
    __shared__ float sLabelScore[BM];
    __shared__ float sBiasS[SPAD];
    __shared__ int   sSamp[SPAD];
    __shared__ int   sLabels[BM];
    __shared__ float sPt[4], sVc[4];

    const int tid  = threadIdx.x;
    const int lane = tid & 63;
    const int w    = tid >> 6;            // wave 0..3
    const int l16  = lane & 15;
    const int g    = lane >> 4;           // 0..3 (k-subgroup)
    const int ctA  = 2 * w;               // col tiles {0,1},{2,3},{4,5},{6,6dup}
    const int ctB  = (w == 3) ? 6 : 2 * w + 1;
    const int rowBase = blockIdx.x * BM;

    if (tid < SPAD) {
        int s = (tid < S) ? samples[tid] : -1;
        sSamp[tid]  = s;
        sBiasS[tid] = (s >= 0) ? bias[s] : 0.0f;
    }
    if (tid < BM) {
        int gr = rowBase + tid;
        sLabels[tid] = (gr < Btot) ? labels[gr] : -100;
    }
    __syncthreads();

    // group mapping: 16-lane group sr owns pred row sr (staging + label dot + softmax)
    const int sr = tid >> 4;              // 0..15
    const int li = tid & 15;              // 0..15
    const float* aSrc = pred + (size_t)min(rowBase + sr, Btot - 1) * D + li * 4;
    const int lab_sr  = sLabels[sr];
    const float lflag = (lab_sr >= 0) ? 1.0f : 0.0f;
    const float* lSrc = proj + (size_t)(lab_sr >= 0 ? lab_sr : 0) * D + li * 4;

    // swizzled LDS addresses (bytes). write: row sr, 16B-unit (li>>1)^(sr&7), half li&1
    const int wByte = sr * 128 + ((((li >> 1) ^ (sr & 7)) << 4)) + ((li & 1) << 3);
    // read: row l16, unit (4*ks+g)^(l16&7)
    const int rByte0 = l16 * 128 + (((g    ) ^ (l16 & 7)) << 4);   // ks=0
    const int rByte1 = l16 * 128 + (((4 + g) ^ (l16 & 7)) << 4);   // ks=1

    const unsigned short* qA = Qb + (size_t)(ctA * 16 + l16) * D + g * 8;
    const unsigned short* qB = Qb + (size_t)(ctB * 16 + l16) * D + g * 8;

    f32x4 acc0 = {0.f,0.f,0.f,0.f}, acc1 = {0.f,0.f,0.f,0.f};
    float lpart = 0.0f;

    const int nCh = D >> 6;               // 12

    // 1-ahead register prefetch (8 VGPR): pred chunk + proj[label] chunk
    float4 pf  = *(const float4*)(aSrc);
    float4 plf = *(const float4*)(lSrc);

    char* ldsBase = (char*)&sAb[0][0][0];

    for (int ck = 0; ck < nCh; ++ck) {
        const int kk  = ck << 6;
        const int boff = (ck & 1) * (BM * 64 * 2);   // 2048 B per buffer

        // pack current pred chunk to bf16 and store swizzled (8 B)
        unsigned int u0 = (unsigned)f2bfu(pf.x) | ((unsigned)f2bfu(pf.y) << 16);
        unsigned int u1 = (unsigned)f2bfu(pf.z) | ((unsigned)f2bfu(pf.w) << 16);
        *(uint2*)(ldsBase + boff + wByte) = make_uint2(u0, u1);

        // label dot with CURRENT chunk (exact f32, from registers)
        lpart += pf.x * plf.x + pf.y * plf.y + pf.z * plf.z + pf.w * plf.w;

        __syncthreads();                  // tile visible; other buffer free

        // prefetch next chunk
        if (ck + 1 < nCh) {
            pf  = *(const float4*)(aSrc + kk + 64);
            plf = *(const float4*)(lSrc + kk + 64);
        }

        // B fragments (L2-resident Qb)
        short8 b00 = *(const short8*)(qA + kk);
        short8 b01 = *(const short8*)(qA + kk + 32);
        short8 b10 = *(const short8*)(qB + kk);
        short8 b11 = *(const short8*)(qB + kk + 32);

        // A fragments: one ds_read_b128 per K-step
        short8 a80 = *(const short8*)(ldsBase + boff + rByte0);
        short8 a81 = *(const short8*)(ldsBase + boff + rByte1);

        acc0 = __builtin_amdgcn_mfma_f32_16x16x32_bf16(a80, b00, acc0, 0, 0, 0);
        acc1 = __builtin_amdgcn_mfma_f32_16x16x32_bf16(a80, b10, acc1, 0, 0, 0);
        acc0 = __builtin_amdgcn_mfma_f32_16x16x32_bf16(a81, b01, acc0, 0, 0, 0);
        acc1 = __builtin_amdgcn_mfma_f32_16x16x32_bf16(a81, b11, acc1, 0, 0, 0);
    }

    // reduce label dot within each 16-lane group
    lpart *= lflag;
    lpart += __shfl_down(lpart, 8, 16);
    lpart += __shfl_down(lpart, 4, 16);
    lpart += __shfl_down(lpart, 2, 16);
    lpart += __shfl_down(lpart, 1, 16);
    if (li == 0)
        sLabelScore[sr] = (lab_sr >= 0) ? (lpart + bias[lab_sr]) : 0.0f;

    // scores -> LDS (C-layout: col = lane&15, row = (lane>>4)*4 + i)
    #pragma unroll
    for (int i = 0; i < 4; ++i) {
        int row = g * 4 + i;
        scores[row * 113 + ctA * 16 + l16] = acc0[i];
        scores[row * 113 + ctB * 16 + l16] = acc1[i];   // w=3 dup write: same val
    }
    __syncthreads();

    // ---- wave-parallel softmax CE: group sr handles row sr, 7 slots/lane ----
    const int  row   = sr;
    const int  lab   = lab_sr;
    const bool valid = (lab != -100) && (rowBase + row < Btot);

    // pass 1: accidental-hit count
    int cnt = 0;
    #pragma unroll
    for (int k = 0; k < 7; ++k) {
        int s = li + 16 * k;
        if (s < S) cnt += (sSamp[s] == lab) ? 1 : 0;
    }
    cnt += __shfl_xor(cnt, 1, 16);
    cnt += __shfl_xor(cnt, 2, 16);
    cnt += __shfl_xor(cnt, 4, 16);
    cnt += __shfl_xor(cnt, 8, 16);

    const float corr = logV1 - __logf((float)(S - cnt));
    const float ls   = sLabelScore[row];

    // pass 2: values + max
    float v7[7];
    float mv = -1e30f;
    #pragma unroll
    for (int k = 0; k < 7; ++k) {
        int s = li + 16 * k;
        float v = -1e30f;
        if (s < S) {
            v = scores[row * 113 + s] + sBiasS[s] + corr;
            if (valid && sSamp[s] == lab) v -= 1000000.0f;
        }
        v7[k] = v;
        mv = fmaxf(mv, v);
    }
    mv = fmaxf(mv, __shfl_xor(mv, 1, 16));
    mv = fmaxf(mv, __shfl_xor(mv, 2, 16));
    mv = fmaxf(mv, __shfl_xor(mv, 4, 16));
    mv = fmaxf(mv, __shfl_xor(mv, 8, 16));
    const float m = fmaxf(mv, ls);

    // pass 3: sum of exps
    float se = 0.0f;
    #pragma unroll
    for (int k = 0; k < 7; ++k)
        se += __expf(v7[k] - m);          // -1e30 pads underflow to 0
    se += __shfl_xor(se, 1, 16);
    se += __shfl_xor(se, 2, 16);
    se += __shfl_xor(se, 4, 16);
    se += __shfl_xor(se, 8, 16);

    float pt = 0.0f, vc = 0.0f;
    if (li == 0 && valid) {
        float set = se + __expf(ls - m);
        pt = m - ls + __logf(set);
        vc = 1.0f;
    }
    // combine the 4 group-leaders of each wave (lanes 0,16,32,48)
    pt += __shfl_down(pt, 16); vc += __shfl_down(vc, 16);
    pt += __shfl_down(pt, 32); vc += __shfl_down(vc, 32);
    if (lane == 0) { sPt[w] = pt; sVc[w] = vc; }
    __syncthreads();
    if (tid == 0) {
        float P = sPt[0] + sPt[1] + sPt[2] + sPt[3];
        float C = sVc[0] + sVc[1] + sVc[2] + sVc[3];
        partials[blockIdx.x]             = P;
        partials[gridDim.x + blockIdx.x] = C;
    }
}

__global__ void ssce_final(const float* __restrict__ partials, int nb,
                           float* __restrict__ out)
{
    __shared__ float red[8];
    int tid = threadIdx.x;
    float s = 0.0f, c = 0.0f;
    for (int i = tid; i < nb; i += 256) {
        s += partials[i];
        c += partials[nb + i];
    }
    #pragma unroll
    for (int off = 32; off > 0; off >>= 1) {
        s += __shfl_down(s, off);
        c += __shfl_down(c, off);
    }
    int wv = tid >> 6;
    if ((tid & 63) == 0) { red[wv * 2] = s; red[wv * 2 + 1] = c; }
    __syncthreads();
    if (tid == 0) {
        float S2 = 0.0f, C2 = 0.0f;
        for (int i = 0; i < 4; ++i) { S2 += red[i * 2]; C2 += red[i * 2 + 1]; }
        out[0] = S2 / fmaxf(C2, 1.0f);
    }
}

extern "C" void kernel_launch(void* const* d_in, const int* in_sizes, int n_in,
                              void* d_out, int out_size, void* d_ws, size_t ws_size,
                              hipStream_t stream)
{
    const float* pred    = (const float*)d_in[0];
    const int*   labels  = (const int*)  d_in[1];
    const float* proj    = (const float*)d_in[2];
    const float* bias    = (const float*)d_in[3];
    const int*   samples = (const int*)  d_in[4];

    const int B = in_sizes[1];
    const int V = in_sizes[3];
    const int S = in_sizes[4];
    const int D = in_sizes[0] / B;        // 768

    float logV1 = logf((float)(V - 1));
    float* partials = (float*)d_ws;                              // 2*grid floats
    unsigned short* Qb = (unsigned short*)((char*)d_ws + 16384);

    ssce_qprep<<<SPAD, 256, 0, stream>>>(proj, samples, Qb, D, S);

    const int grid = (B + BM - 1) / BM;   // 1024 -> 4 blocks/CU
    ssce_main<<<grid, NTHREADS, 0, stream>>>(pred, labels, proj, bias, samples,
                                             Qb, partials, B, D, S, logV1);
    ssce_final<<<1, 256, 0, stream>>>(partials, grid, (float*)d_out);
}